// Round 8
// baseline (302.510 us; speedup 1.0000x reference)
//
#include <hip/hip_runtime.h>
#include <hip/hip_fp16.h>
#include <math.h>

#define D 64
#define LN_EPS 1e-5f
#define SCAN_CH 1024
#define WFIX 262144.0f    // 2^18 fixed-point scale for wsum in packed
#define CNT_SH 25         // count in bits 25..31, wsum in bits 0..24
#define WSUM_MASK ((1u << CNT_SH) - 1)
#define WQ_BITS 15        // csr weight quantization (w in [0,1))
#define WQ_SCALE 32768.0f
#define CAP 64            // fixed CSR capacity per node
#define CAP_SH 6

// ---------------------------------------------------------------------------
// Fixed-capacity CSR pipeline (6 launches):
//   memset(packed) -> build(atomic cnt|wsum -> rank -> csr[dst*64+rank]) ->
//   gemm(y fp16, dis from packed) -> gather(+bias+partials) -> redux -> ln
// csr entry: u32 = (src << 15) | round(w * 2^15)
// ws: packed u32[N] | scal double[2] | partial float[2*gb] | y half[N*D] |
//     csr u32[N*CAP]
// ---------------------------------------------------------------------------

__global__ __launch_bounds__(256) void k_build(const int* __restrict__ ei,
                                               const float* __restrict__ w,
                                               unsigned int* __restrict__ packed,
                                               unsigned int* __restrict__ csr, int E) {
    int e = blockIdx.x * blockDim.x + threadIdx.x;
    if (e < E) {
        int dst = ei[E + e];
        float wf = w[e];
        unsigned int v = (1u << CNT_SH) | __float2uint_rn(wf * WFIX);
        unsigned int old = atomicAdd(&packed[dst], v);
        unsigned int rank = old >> CNT_SH;
        if (csr != nullptr && rank < CAP) {
            unsigned int wq = __float2uint_rn(wf * WQ_SCALE);
            if (wq > 32767u) wq = 32767u;
            csr[((size_t)dst << CAP_SH) + rank] =
                ((unsigned int)ei[e] << WQ_BITS) | wq;
        }
    }
}

// ---- y[n,c] = dis[n] * sum_k x[n,k]*W[c,k], output fp16 -------------------
// 64 rows/block, 256 threads, thread = 4 rows x 4 strided cols (c1 + 16*jc).
// W row-major in LDS; float4 dot along k => all LDS traffic <=2-way aliased.
__global__ __launch_bounds__(256, 4) void k_gemm(const float* __restrict__ x,
                                                 const float* __restrict__ W,
                                                 const unsigned int* __restrict__ packed,
                                                 __half* __restrict__ y, int N) {
    __shared__ float Ws[D * 68];       // Ws[c*68+k]
    __shared__ float xs[64 * 68];      // xs[r*68+k]
    int tid = threadIdx.x;
    int rowBase = blockIdx.x * 64;
#pragma unroll
    for (int i = 0; i < 16; ++i) {
        int idx = i * 256 + tid;
        int a = idx >> 6, kk = idx & 63;
        Ws[a * 68 + kk] = W[idx];
        int row = rowBase + a;
        xs[a * 68 + kk] = (row < N) ? x[idx + rowBase * D] : 0.0f;
    }
    __syncthreads();
    int l = tid & 63, wv = tid >> 6;
    int g = l >> 4;
    int c1 = l & 15;
    int r0 = wv * 16 + g * 4;
    float acc[4][4];
#pragma unroll
    for (int a = 0; a < 4; ++a)
#pragma unroll
        for (int bj = 0; bj < 4; ++bj) acc[a][bj] = 0.0f;
#pragma unroll 2
    for (int kc = 0; kc < 16; ++kc) {
        int k0 = kc * 4;
        float4 xr[4], wr[4];
#pragma unroll
        for (int jr = 0; jr < 4; ++jr)
            xr[jr] = *(const float4*)&xs[(r0 + jr) * 68 + k0];
#pragma unroll
        for (int jc = 0; jc < 4; ++jc)
            wr[jc] = *(const float4*)&Ws[(c1 + 16 * jc) * 68 + k0];
#pragma unroll
        for (int jr = 0; jr < 4; ++jr)
#pragma unroll
            for (int jc = 0; jc < 4; ++jc)
                acc[jr][jc] += xr[jr].x * wr[jc].x + xr[jr].y * wr[jc].y +
                               xr[jr].z * wr[jc].z + xr[jr].w * wr[jc].w;
    }
#pragma unroll
    for (int jr = 0; jr < 4; ++jr) {
        int row = rowBase + r0 + jr;
        if (row < N) {
            float dr = rsqrtf(1.0f +
                (float)(packed[row] & WSUM_MASK) * (1.0f / WFIX));
#pragma unroll
            for (int jc = 0; jc < 4; ++jc)
                y[row * D + c1 + 16 * jc] = __float2half_rn(acc[jr][jc] * dr);
        }
    }
}

// ---- gather: one wave/node, lane = feature; fixed-stride csr (cnt<=64) ----
__global__ __launch_bounds__(256) void k_gather(const unsigned int* __restrict__ packed,
                                                const unsigned int* __restrict__ csr,
                                                const __half* __restrict__ y,
                                                const float* __restrict__ b,
                                                float* __restrict__ out,
                                                float* __restrict__ partial, int N) {
    int wid = (blockIdx.x * 256 + threadIdx.x) >> 6;
    int lane = threadIdx.x & 63;
    float s = 0.0f, ss = 0.0f;
    if (wid < N) {
        int n = wid;
        unsigned int p = packed[n];
        int m = (int)(p >> CNT_SH);
        if (m > CAP) m = CAP;
        float dis_n = rsqrtf(1.0f + (float)(p & WSUM_MASK) * (1.0f / WFIX));
        float acc = __half2float(y[(size_t)n * D + lane]);   // self-loop term
        const float wsc = 1.0f / WQ_SCALE;
        size_t base0 = (size_t)n << CAP_SH;
        unsigned int pe = (lane < m) ? csr[base0 + lane] : 0u;
        int j = 0;
        for (; j + 3 < m; j += 4) {
            unsigned int p0 = __shfl(pe, j);
            unsigned int p1 = __shfl(pe, j + 1);
            unsigned int p2 = __shfl(pe, j + 2);
            unsigned int p3 = __shfl(pe, j + 3);
            float a0 = __half2float(y[(size_t)(p0 >> WQ_BITS) * D + lane]);
            float a1 = __half2float(y[(size_t)(p1 >> WQ_BITS) * D + lane]);
            float a2 = __half2float(y[(size_t)(p2 >> WQ_BITS) * D + lane]);
            float a3 = __half2float(y[(size_t)(p3 >> WQ_BITS) * D + lane]);
            acc += (float)(p0 & 32767u) * wsc * a0;
            acc += (float)(p1 & 32767u) * wsc * a1;
            acc += (float)(p2 & 32767u) * wsc * a2;
            acc += (float)(p3 & 32767u) * wsc * a3;
        }
        for (; j < m; ++j) {
            unsigned int p0 = __shfl(pe, j);
            float a0 = __half2float(y[(size_t)(p0 >> WQ_BITS) * D + lane]);
            acc += (float)(p0 & 32767u) * wsc * a0;
        }
        float o = dis_n * acc + b[lane];
        out[(size_t)n * D + lane] = o;
        s = o;
        ss = o * o;
    }
#pragma unroll
    for (int off = 32; off; off >>= 1) {
        s += __shfl_down(s, off);
        ss += __shfl_down(ss, off);
    }
    __shared__ float ls[4], lss[4];
    int wv = threadIdx.x >> 6;
    if (lane == 0) { ls[wv] = s; lss[wv] = ss; }
    __syncthreads();
    if (threadIdx.x == 0) {
        partial[2 * blockIdx.x]     = ls[0] + ls[1] + ls[2] + ls[3];
        partial[2 * blockIdx.x + 1] = lss[0] + lss[1] + lss[2] + lss[3];
    }
}

__global__ __launch_bounds__(SCAN_CH) void k_redux(const float* __restrict__ partial,
                                                   int nb, double* __restrict__ scal) {
    double s = 0.0, ss = 0.0;
    for (int i = threadIdx.x; i < nb; i += SCAN_CH) {
        s += (double)partial[2 * i];
        ss += (double)partial[2 * i + 1];
    }
#pragma unroll
    for (int off = 32; off; off >>= 1) {
        s += __shfl_down(s, off);
        ss += __shfl_down(ss, off);
    }
    __shared__ double ls[SCAN_CH / 64], lss[SCAN_CH / 64];
    int lane = threadIdx.x & 63, wv = threadIdx.x >> 6;
    if (lane == 0) { ls[wv] = s; lss[wv] = ss; }
    __syncthreads();
    if (threadIdx.x == 0) {
        double S = 0.0, SS = 0.0;
        for (int k = 0; k < SCAN_CH / 64; ++k) { S += ls[k]; SS += lss[k]; }
        scal[0] = S;
        scal[1] = SS;
    }
}

// ---- graph LayerNorm + ReLU, in place ----
__global__ __launch_bounds__(256) void k_ln(float* __restrict__ out,
                                            const float* __restrict__ gamma,
                                            const float* __restrict__ beta,
                                            const double* __restrict__ scal, int N) {
    int nchunks = N * (D / 4);
    int i = blockIdx.x * blockDim.x + threadIdx.x;
    if (i >= nchunks) return;
    double M = (double)N * (double)D;
    double mu = scal[0] / M;
    double var = scal[1] / M - mu * mu;
    float muf = (float)mu;
    float isd = (float)(1.0 / sqrt(var + (double)LN_EPS));
    int c4 = (i & 15) * 4;
    float4 v = ((float4*)out)[i];
    v.x = fmaxf((v.x - muf) * isd * gamma[c4 + 0] + beta[c4 + 0], 0.0f);
    v.y = fmaxf((v.y - muf) * isd * gamma[c4 + 1] + beta[c4 + 1], 0.0f);
    v.z = fmaxf((v.z - muf) * isd * gamma[c4 + 2] + beta[c4 + 2], 0.0f);
    v.w = fmaxf((v.w - muf) * isd * gamma[c4 + 3] + beta[c4 + 3], 0.0f);
    ((float4*)out)[i] = v;
}

// ---- fallback kernels (atomic scatter), used only if csr path unsafe ----
__global__ __launch_bounds__(256) void k_scatter(const int* __restrict__ ei,
                                                 const float* __restrict__ w,
                                                 const __half* __restrict__ y,
                                                 float* __restrict__ out, int E) {
    int t = blockIdx.x * blockDim.x + threadIdx.x;
    int e = t >> 6;
    int lane = t & 63;
    if (e >= E) return;
    float v = w[e] * __half2float(y[(size_t)ei[e] * D + lane]);
    unsafeAtomicAdd(&out[(size_t)ei[E + e] * D + lane], v);
}

__global__ __launch_bounds__(256) void k_seed(const __half* __restrict__ y,
                                              float* __restrict__ out, int total) {
    int i = blockIdx.x * blockDim.x + threadIdx.x;
    if (i < total) out[i] = __half2float(y[i]);
}

__global__ __launch_bounds__(256) void k_finalize(float* __restrict__ out,
                                                  const unsigned int* __restrict__ packed,
                                                  const float* __restrict__ b,
                                                  double* __restrict__ scal, int N) {
    int nchunks = N * (D / 4);
    float s = 0.0f, ss = 0.0f;
    float4* o4 = (float4*)out;
    for (int i = blockIdx.x * blockDim.x + threadIdx.x; i < nchunks;
         i += gridDim.x * blockDim.x) {
        int row = i >> 4;
        int c4 = (i & 15) * 4;
        float4 v = o4[i];
        float dr = rsqrtf(1.0f + (float)(packed[row] & WSUM_MASK) * (1.0f / WFIX));
        v.x = dr * v.x + b[c4 + 0];
        v.y = dr * v.y + b[c4 + 1];
        v.z = dr * v.z + b[c4 + 2];
        v.w = dr * v.w + b[c4 + 3];
        o4[i] = v;
        s += v.x + v.y + v.z + v.w;
        ss += v.x * v.x + v.y * v.y + v.z * v.z + v.w * v.w;
    }
#pragma unroll
    for (int off = 32; off; off >>= 1) {
        s += __shfl_down(s, off);
        ss += __shfl_down(ss, off);
    }
    __shared__ float ls[4], lss[4];
    int lane = threadIdx.x & 63, wv = threadIdx.x >> 6;
    if (lane == 0) { ls[wv] = s; lss[wv] = ss; }
    __syncthreads();
    if (threadIdx.x == 0) {
        atomicAdd(&scal[0], (double)(ls[0] + ls[1] + ls[2] + ls[3]));
        atomicAdd(&scal[1], (double)(lss[0] + lss[1] + lss[2] + lss[3]));
    }
}

extern "C" void kernel_launch(void* const* d_in, const int* in_sizes, int n_in,
                              void* d_out, int out_size, void* d_ws, size_t ws_size,
                              hipStream_t stream) {
    const float* x     = (const float*)d_in[0];
    const int*   ei    = (const int*)d_in[1];
    const float* ew    = (const float*)d_in[2];
    const float* W     = (const float*)d_in[3];
    const float* b     = (const float*)d_in[4];
    const float* gamma = (const float*)d_in[5];
    const float* beta  = (const float*)d_in[6];
    float* out = (float*)d_out;

    int N = in_sizes[0] / D;
    int E = in_sizes[2];
    int gb = (N + 3) / 4;                        // gather blocks (4 waves each)

    char* ws = (char*)d_ws;
    size_t off = 0;
    unsigned int* packed = (unsigned int*)(ws + off); off += (size_t)N * 4;
    double* scal = (double*)(ws + off); off += 16;
    float* partial = (float*)(ws + off); off += (size_t)gb * 8;
    off = (off + 255) & ~(size_t)255;
    __half* y    = (__half*)(ws + off); off += (size_t)N * D * 2;
    off = (off + 255) & ~(size_t)255;
    unsigned int* csr = (unsigned int*)(ws + off); off += (size_t)N * CAP * 4;

    // csr path safety: ws fits, src fits in 32-WQ_BITS bits, and mean degree
    // low enough that P(deg >= CAP) is negligible (E <= 24*N -> ~1e-5 risk).
    bool csr_path = (ws_size >= off) && (N < (1 << (32 - WQ_BITS))) &&
                    ((size_t)E <= (size_t)N * 24);

    hipMemsetAsync(packed, 0, (size_t)N * 4, stream);

    if (csr_path) {
        k_build<<<(E + 255) / 256, 256, 0, stream>>>(ei, ew, packed, csr, E);
        k_gemm<<<(N + 63) / 64, 256, 0, stream>>>(x, W, packed, y, N);
        k_gather<<<gb, 256, 0, stream>>>(packed, csr, y, b, out, partial, N);
        k_redux<<<1, SCAN_CH, 0, stream>>>(partial, gb, scal);
        k_ln<<<(N * (D / 4) + 255) / 256, 256, 0, stream>>>(out, gamma, beta, scal, N);
    } else {
        hipMemsetAsync(scal, 0, 16, stream);
        k_build<<<(E + 255) / 256, 256, 0, stream>>>(ei, ew, packed, nullptr, E);
        k_gemm<<<(N + 63) / 64, 256, 0, stream>>>(x, W, packed, y, N);
        k_seed<<<(N * D + 255) / 256, 256, 0, stream>>>(y, out, N * D);
        k_scatter<<<(E + 3) / 4, 256, 0, stream>>>(ei, ew, y, out, E);
        k_finalize<<<2048, 256, 0, stream>>>(out, packed, b, scal, N);
        k_ln<<<(N * (D / 4) + 255) / 256, 256, 0, stream>>>(out, gamma, beta, scal, N);
    }
}

// Round 9
// 241.551 us; speedup vs baseline: 1.2524x; 1.2524x over previous
//
#include <hip/hip_runtime.h>
#include <hip/hip_fp16.h>
#include <math.h>

#define D 64
#define LN_EPS 1e-5f
#define SCAN_CH 1024
#define WFIX 262144.0f    // 2^18 fixed-point scale for wsum
#define CNT_SH 25         // count in bits 25..31, wsum in bits 0..24
#define WSUM_MASK ((1u << CNT_SH) - 1)
#define WQ_BITS 15        // csr weight quantization (w in [0,1))
#define WQ_SCALE 32768.0f
#define NB 1024           // coarse buckets
#define BSH 7             // 128 nodes per bucket
#define GP 256            // partition grid blocks

// ---------------------------------------------------------------------------
// Bucket-partition pipeline (zero global atomics):
//  k_hist1: per-block LDS hist over 1024 buckets (bucket = dst>>7)
//  k_scanb: per-bucket exclusive scan over 256 block counts (wave shuffle)
//  k_scan_base: exclusive scan of 1024 bucket totals
//  k_part: edges -> u64 recs into contiguous per-(bucket,block) ranges
//  k_emit: per-bucket: LDS cnt|wsum -> packed, nstart, compact csr
//  k_gemm(y fp16) -> k_gather(+bias+partials) -> k_redux -> k_ln
// rec u64: hi = dst_local(7) | wfix(19)<<7 ; lo = src(17)<<15 | wq(15)
// ws: packed u32[N] | nstart int[N] | hist int[NB*GP] | total int[NB] |
//     scal double[2] | partial float[2*gb] | {part u64[E] ALIAS y half[N*D]} |
//     csr u32[E]
// ---------------------------------------------------------------------------

__global__ __launch_bounds__(256) void k_hist1(const int* __restrict__ ei, int E,
                                               int* __restrict__ hist) {
    __shared__ int h[NB];
    for (int i = threadIdx.x; i < NB; i += 256) h[i] = 0;
    __syncthreads();
    int chunk = (E + GP - 1) / GP;
    int s0 = blockIdx.x * chunk;
    int s1 = min(E, s0 + chunk);
    for (int e = s0 + threadIdx.x; e < s1; e += 256)
        atomicAdd(&h[((unsigned int)ei[E + e]) >> BSH], 1);
    __syncthreads();
    for (int i = threadIdx.x; i < NB; i += 256)
        hist[i * GP + blockIdx.x] = h[i];          // bucket-major
}

// per-bucket exclusive scan over GP=256 block counts; wave handles one bucket
__global__ __launch_bounds__(256) void k_scanb(int* __restrict__ hist,
                                               int* __restrict__ total) {
    int lane = threadIdx.x & 63, wv = threadIdx.x >> 6;
    int bucket = blockIdx.x * 4 + wv;
    int4 c = *(int4*)&hist[bucket * GP + lane * 4];
    int lsum = c.x + c.y + c.z + c.w;
    int sum = lsum;
#pragma unroll
    for (int off2 = 1; off2 < 64; off2 <<= 1) {
        int t = __shfl_up(sum, off2);
        if (lane >= off2) sum += t;
    }
    int base = sum - lsum;
    int4 o;
    o.x = base; o.y = base + c.x; o.z = o.y + c.y; o.w = o.z + c.z;
    *(int4*)&hist[bucket * GP + lane * 4] = o;     // exclusive offsets in place
    if (lane == 63) total[bucket] = sum;           // bucket total
}

__global__ __launch_bounds__(SCAN_CH) void k_scan_base(int* __restrict__ psum, int nblk) {
    __shared__ int s[SCAN_CH];
    int tid = threadIdx.x;
    s[tid] = (tid < nblk) ? psum[tid] : 0;
    __syncthreads();
    int own = s[tid];
    for (int off = 1; off < SCAN_CH; off <<= 1) {
        int t = (tid >= off) ? s[tid - off] : 0;
        __syncthreads();
        s[tid] += t;
        __syncthreads();
    }
    if (tid < nblk) psum[tid] = s[tid] - own;      // exclusive
}

// partition edges into contiguous per-(bucket,block) ranges
__global__ __launch_bounds__(256) void k_part(const int* __restrict__ ei,
                                              const float* __restrict__ w,
                                              const int* __restrict__ hist,
                                              const int* __restrict__ total,
                                              unsigned long long* __restrict__ part,
                                              int E) {
    __shared__ int cur[NB];
    for (int i = threadIdx.x; i < NB; i += 256)
        cur[i] = total[i] + hist[i * GP + blockIdx.x];
    __syncthreads();
    int chunk = (E + GP - 1) / GP;
    int s0 = blockIdx.x * chunk;
    int s1 = min(E, s0 + chunk);
    for (int e = s0 + threadIdx.x; e < s1; e += 256) {
        unsigned int dst = (unsigned int)ei[E + e];
        unsigned int src = (unsigned int)ei[e];
        float wf = w[e];
        int pos = atomicAdd(&cur[dst >> BSH], 1);
        unsigned int wq = __float2uint_rn(wf * WQ_SCALE);
        if (wq > 32767u) wq = 32767u;
        unsigned int wfix = __float2uint_rn(wf * WFIX);
        unsigned int lo = (src << WQ_BITS) | wq;
        unsigned int hi = (dst & ((1u << BSH) - 1)) | (wfix << BSH);
        part[pos] = ((unsigned long long)hi << 32) | lo;
    }
}

// per-bucket: counts/wsum in LDS -> packed + nstart + compact csr
__global__ __launch_bounds__(256) void k_emit(const unsigned long long* __restrict__ part,
                                              const int* __restrict__ total,
                                              unsigned int* __restrict__ packed,
                                              int* __restrict__ nstart,
                                              unsigned int* __restrict__ csr,
                                              int N, int E) {
    __shared__ unsigned int cw[1 << BSH];
    __shared__ int cursor[1 << BSH];
    __shared__ int wtot[2];
    int b = blockIdx.x;
    int beg = total[b];
    int end = (b == NB - 1) ? E : total[b + 1];
    int tid = threadIdx.x;
    if (tid < (1 << BSH)) cw[tid] = 0;
    __syncthreads();
    for (int i = beg + tid; i < end; i += 256) {
        unsigned int hi = (unsigned int)(part[i] >> 32);
        atomicAdd(&cw[hi & 127u], (1u << CNT_SH) | (hi >> BSH));
    }
    __syncthreads();
    int lane = tid & 63, wv = tid >> 6;
    if (tid < 128) {                    // waves 0,1: scan 128 counts
        unsigned int p = cw[tid];
        int cnt = (int)(p >> CNT_SH);
        int sum = cnt;
#pragma unroll
        for (int off2 = 1; off2 < 64; off2 <<= 1) {
            int t = __shfl_up(sum, off2);
            if (lane >= off2) sum += t;
        }
        if (lane == 63) wtot[wv] = sum;
        cursor[tid] = sum - cnt;        // exclusive within wave
        int node = (b << BSH) + tid;
        if (node < N) packed[node] = p;
    }
    __syncthreads();
    if (tid < 128) {
        int st = cursor[tid] + beg + ((wv == 1) ? wtot[0] : 0);
        cursor[tid] = st;
        int node = (b << BSH) + tid;
        if (node < N) nstart[node] = st;
    }
    __syncthreads();
    for (int i = beg + tid; i < end; i += 256) {
        unsigned long long r = part[i];
        unsigned int hi = (unsigned int)(r >> 32);
        int pos = atomicAdd(&cursor[hi & 127u], 1);
        csr[pos] = (unsigned int)r;
    }
}

// ---- y[n,c] = dis[n] * sum_k x[n,k]*W[c,k], output fp16 -------------------
__global__ __launch_bounds__(256, 4) void k_gemm(const float* __restrict__ x,
                                                 const float* __restrict__ W,
                                                 const unsigned int* __restrict__ packed,
                                                 __half* __restrict__ y, int N) {
    __shared__ float Ws[D * 68];
    __shared__ float xs[64 * 68];
    int tid = threadIdx.x;
    int rowBase = blockIdx.x * 64;
#pragma unroll
    for (int i = 0; i < 16; ++i) {
        int idx = i * 256 + tid;
        int a = idx >> 6, kk = idx & 63;
        Ws[a * 68 + kk] = W[idx];
        int row = rowBase + a;
        xs[a * 68 + kk] = (row < N) ? x[idx + rowBase * D] : 0.0f;
    }
    __syncthreads();
    int l = tid & 63, wv = tid >> 6;
    int g = l >> 4;
    int c1 = l & 15;
    int r0 = wv * 16 + g * 4;
    float acc[4][4];
#pragma unroll
    for (int a = 0; a < 4; ++a)
#pragma unroll
        for (int bj = 0; bj < 4; ++bj) acc[a][bj] = 0.0f;
#pragma unroll 2
    for (int kc = 0; kc < 16; ++kc) {
        int k0 = kc * 4;
        float4 xr[4], wr[4];
#pragma unroll
        for (int jr = 0; jr < 4; ++jr)
            xr[jr] = *(const float4*)&xs[(r0 + jr) * 68 + k0];
#pragma unroll
        for (int jc = 0; jc < 4; ++jc)
            wr[jc] = *(const float4*)&Ws[(c1 + 16 * jc) * 68 + k0];
#pragma unroll
        for (int jr = 0; jr < 4; ++jr)
#pragma unroll
            for (int jc = 0; jc < 4; ++jc)
                acc[jr][jc] += xr[jr].x * wr[jc].x + xr[jr].y * wr[jc].y +
                               xr[jr].z * wr[jc].z + xr[jr].w * wr[jc].w;
    }
#pragma unroll
    for (int jr = 0; jr < 4; ++jr) {
        int row = rowBase + r0 + jr;
        if (row < N) {
            float dr = rsqrtf(1.0f +
                (float)(packed[row] & WSUM_MASK) * (1.0f / WFIX));
#pragma unroll
            for (int jc = 0; jc < 4; ++jc)
                y[row * D + c1 + 16 * jc] = __float2half_rn(acc[jr][jc] * dr);
        }
    }
}

// ---- gather: one wave/node, lane = feature; compact csr -------------------
__global__ __launch_bounds__(256) void k_gather(const unsigned int* __restrict__ packed,
                                                const int* __restrict__ nstart,
                                                const unsigned int* __restrict__ csr,
                                                const __half* __restrict__ y,
                                                const float* __restrict__ b,
                                                float* __restrict__ out,
                                                float* __restrict__ partial, int N) {
    int wid = (blockIdx.x * 256 + threadIdx.x) >> 6;
    int lane = threadIdx.x & 63;
    float s = 0.0f, ss = 0.0f;
    if (wid < N) {
        int n = wid;
        unsigned int p = packed[n];
        int m = (int)(p >> CNT_SH);
        int start = nstart[n];
        float dis_n = rsqrtf(1.0f + (float)(p & WSUM_MASK) * (1.0f / WFIX));
        float acc = __half2float(y[(size_t)n * D + lane]);   // self-loop term
        const float wsc = 1.0f / WQ_SCALE;
        for (int base0 = start; base0 < start + m; base0 += 64) {
            int mm = start + m - base0; if (mm > 64) mm = 64;
            unsigned int pe = (lane < mm) ? csr[base0 + lane] : 0u;
            int j = 0;
            for (; j + 3 < mm; j += 4) {
                unsigned int p0 = __shfl(pe, j);
                unsigned int p1 = __shfl(pe, j + 1);
                unsigned int p2 = __shfl(pe, j + 2);
                unsigned int p3 = __shfl(pe, j + 3);
                float a0 = __half2float(y[(size_t)(p0 >> WQ_BITS) * D + lane]);
                float a1 = __half2float(y[(size_t)(p1 >> WQ_BITS) * D + lane]);
                float a2 = __half2float(y[(size_t)(p2 >> WQ_BITS) * D + lane]);
                float a3 = __half2float(y[(size_t)(p3 >> WQ_BITS) * D + lane]);
                acc += (float)(p0 & 32767u) * wsc * a0;
                acc += (float)(p1 & 32767u) * wsc * a1;
                acc += (float)(p2 & 32767u) * wsc * a2;
                acc += (float)(p3 & 32767u) * wsc * a3;
            }
            for (; j < mm; ++j) {
                unsigned int p0 = __shfl(pe, j);
                acc += (float)(p0 & 32767u) * wsc *
                       __half2float(y[(size_t)(p0 >> WQ_BITS) * D + lane]);
            }
        }
        float o = dis_n * acc + b[lane];
        out[(size_t)n * D + lane] = o;
        s = o;
        ss = o * o;
    }
#pragma unroll
    for (int off = 32; off; off >>= 1) {
        s += __shfl_down(s, off);
        ss += __shfl_down(ss, off);
    }
    __shared__ float ls[4], lss[4];
    int wv = threadIdx.x >> 6;
    if (lane == 0) { ls[wv] = s; lss[wv] = ss; }
    __syncthreads();
    if (threadIdx.x == 0) {
        partial[2 * blockIdx.x]     = ls[0] + ls[1] + ls[2] + ls[3];
        partial[2 * blockIdx.x + 1] = lss[0] + lss[1] + lss[2] + lss[3];
    }
}

__global__ __launch_bounds__(SCAN_CH) void k_redux(const float* __restrict__ partial,
                                                   int nb, double* __restrict__ scal) {
    double s = 0.0, ss = 0.0;
    for (int i = threadIdx.x; i < nb; i += SCAN_CH) {
        s += (double)partial[2 * i];
        ss += (double)partial[2 * i + 1];
    }
#pragma unroll
    for (int off = 32; off; off >>= 1) {
        s += __shfl_down(s, off);
        ss += __shfl_down(ss, off);
    }
    __shared__ double ls[SCAN_CH / 64], lss[SCAN_CH / 64];
    int lane = threadIdx.x & 63, wv = threadIdx.x >> 6;
    if (lane == 0) { ls[wv] = s; lss[wv] = ss; }
    __syncthreads();
    if (threadIdx.x == 0) {
        double S = 0.0, SS = 0.0;
        for (int k = 0; k < SCAN_CH / 64; ++k) { S += ls[k]; SS += lss[k]; }
        scal[0] = S;
        scal[1] = SS;
    }
}

__global__ __launch_bounds__(256) void k_ln(float* __restrict__ out,
                                            const float* __restrict__ gamma,
                                            const float* __restrict__ beta,
                                            const double* __restrict__ scal, int N) {
    int nchunks = N * (D / 4);
    int i = blockIdx.x * blockDim.x + threadIdx.x;
    if (i >= nchunks) return;
    double M = (double)N * (double)D;
    double mu = scal[0] / M;
    double var = scal[1] / M - mu * mu;
    float muf = (float)mu;
    float isd = (float)(1.0 / sqrt(var + (double)LN_EPS));
    int c4 = (i & 15) * 4;
    float4 v = ((float4*)out)[i];
    v.x = fmaxf((v.x - muf) * isd * gamma[c4 + 0] + beta[c4 + 0], 0.0f);
    v.y = fmaxf((v.y - muf) * isd * gamma[c4 + 1] + beta[c4 + 1], 0.0f);
    v.z = fmaxf((v.z - muf) * isd * gamma[c4 + 2] + beta[c4 + 2], 0.0f);
    v.w = fmaxf((v.w - muf) * isd * gamma[c4 + 3] + beta[c4 + 3], 0.0f);
    ((float4*)out)[i] = v;
}

// ---- fallback kernels (atomic scatter), used only if csr path unsafe ----
__global__ __launch_bounds__(256) void k_build(const int* __restrict__ ei,
                                               const float* __restrict__ w,
                                               unsigned int* __restrict__ packed,
                                               int E) {
    int e = blockIdx.x * blockDim.x + threadIdx.x;
    if (e < E) {
        unsigned int v = (1u << CNT_SH) | __float2uint_rn(w[e] * WFIX);
        atomicAdd(&packed[ei[E + e]], v);
    }
}

__global__ __launch_bounds__(256) void k_scatter(const int* __restrict__ ei,
                                                 const float* __restrict__ w,
                                                 const __half* __restrict__ y,
                                                 float* __restrict__ out, int E) {
    int t = blockIdx.x * blockDim.x + threadIdx.x;
    int e = t >> 6;
    int lane = t & 63;
    if (e >= E) return;
    float v = w[e] * __half2float(y[(size_t)ei[e] * D + lane]);
    unsafeAtomicAdd(&out[(size_t)ei[E + e] * D + lane], v);
}

__global__ __launch_bounds__(256) void k_seed(const __half* __restrict__ y,
                                              float* __restrict__ out, int total) {
    int i = blockIdx.x * blockDim.x + threadIdx.x;
    if (i < total) out[i] = __half2float(y[i]);
}

__global__ __launch_bounds__(256) void k_finalize(float* __restrict__ out,
                                                  const unsigned int* __restrict__ packed,
                                                  const float* __restrict__ b,
                                                  double* __restrict__ scal, int N) {
    int nchunks = N * (D / 4);
    float s = 0.0f, ss = 0.0f;
    float4* o4 = (float4*)out;
    for (int i = blockIdx.x * blockDim.x + threadIdx.x; i < nchunks;
         i += gridDim.x * blockDim.x) {
        int row = i >> 4;
        int c4 = (i & 15) * 4;
        float4 v = o4[i];
        float dr = rsqrtf(1.0f + (float)(packed[row] & WSUM_MASK) * (1.0f / WFIX));
        v.x = dr * v.x + b[c4 + 0];
        v.y = dr * v.y + b[c4 + 1];
        v.z = dr * v.z + b[c4 + 2];
        v.w = dr * v.w + b[c4 + 3];
        o4[i] = v;
        s += v.x + v.y + v.z + v.w;
        ss += v.x * v.x + v.y * v.y + v.z * v.z + v.w * v.w;
    }
#pragma unroll
    for (int off = 32; off; off >>= 1) {
        s += __shfl_down(s, off);
        ss += __shfl_down(ss, off);
    }
    __shared__ float ls[4], lss[4];
    int lane = threadIdx.x & 63, wv = threadIdx.x >> 6;
    if (lane == 0) { ls[wv] = s; lss[wv] = ss; }
    __syncthreads();
    if (threadIdx.x == 0) {
        atomicAdd(&scal[0], (double)(ls[0] + ls[1] + ls[2] + ls[3]));
        atomicAdd(&scal[1], (double)(lss[0] + lss[1] + lss[2] + lss[3]));
    }
}

extern "C" void kernel_launch(void* const* d_in, const int* in_sizes, int n_in,
                              void* d_out, int out_size, void* d_ws, size_t ws_size,
                              hipStream_t stream) {
    const float* x     = (const float*)d_in[0];
    const int*   ei    = (const int*)d_in[1];
    const float* ew    = (const float*)d_in[2];
    const float* W     = (const float*)d_in[3];
    const float* b     = (const float*)d_in[4];
    const float* gamma = (const float*)d_in[5];
    const float* beta  = (const float*)d_in[6];
    float* out = (float*)d_out;

    int N = in_sizes[0] / D;
    int E = in_sizes[2];
    int gb = (N + 3) / 4;

    char* ws = (char*)d_ws;
    size_t off = 0;
    unsigned int* packed = (unsigned int*)(ws + off); off += (size_t)N * 4;
    int* nstart  = (int*)(ws + off);    off += (size_t)N * 4;
    int* hist    = (int*)(ws + off);    off += (size_t)NB * GP * 4;
    int* total   = (int*)(ws + off);    off += (size_t)NB * 4;
    double* scal = (double*)(ws + off); off += 16;
    float* partial = (float*)(ws + off); off += (size_t)gb * 8;
    off = (off + 255) & ~(size_t)255;
    size_t partBytes = (size_t)E * 8;
    size_t yBytes = (size_t)N * D * 2;
    unsigned long long* part = (unsigned long long*)(ws + off);
    __half* y = (__half*)(ws + off);
    off += (partBytes > yBytes) ? partBytes : yBytes;   // part dead before gemm
    off = (off + 255) & ~(size_t)255;
    unsigned int* csr = (unsigned int*)(ws + off); off += (size_t)E * 4;

    int nbu = (N + (1 << BSH) - 1) >> BSH;   // used buckets
    bool csr_path = (ws_size >= off) && (N <= (1 << 17)) && (nbu <= NB) &&
                    ((size_t)E <= (size_t)N * 24);

    if (csr_path) {
        k_hist1<<<GP, 256, 0, stream>>>(ei, E, hist);
        k_scanb<<<NB / 4, 256, 0, stream>>>(hist, total);
        k_scan_base<<<1, SCAN_CH, 0, stream>>>(total, NB);
        k_part<<<GP, 256, 0, stream>>>(ei, ew, hist, total, part, E);
        k_emit<<<nbu, 256, 0, stream>>>(part, total, packed, nstart, csr, N, E);
        k_gemm<<<(N + 63) / 64, 256, 0, stream>>>(x, W, packed, y, N);
        k_gather<<<gb, 256, 0, stream>>>(packed, nstart, csr, y, b, out, partial, N);
        k_redux<<<1, SCAN_CH, 0, stream>>>(partial, gb, scal);
        k_ln<<<(N * (D / 4) + 255) / 256, 256, 0, stream>>>(out, gamma, beta, scal, N);
    } else {
        hipMemsetAsync(packed, 0, (size_t)N * 4, stream);
        hipMemsetAsync(scal, 0, 16, stream);
        k_build<<<(E + 255) / 256, 256, 0, stream>>>(ei, ew, packed, E);
        k_gemm<<<(N + 63) / 64, 256, 0, stream>>>(x, W, packed, y, N);
        k_seed<<<(N * D + 255) / 256, 256, 0, stream>>>(y, out, N * D);
        k_scatter<<<(E + 3) / 4, 256, 0, stream>>>(ei, ew, y, out, E);
        k_finalize<<<2048, 256, 0, stream>>>(out, packed, b, scal, N);
        k_ln<<<(N * (D / 4) + 255) / 256, 256, 0, stream>>>(out, gamma, beta, scal, N);
    }
}

// Round 11
// 221.409 us; speedup vs baseline: 1.3663x; 1.0910x over previous
//
#include <hip/hip_runtime.h>
#include <hip/hip_fp16.h>
#include <math.h>

#define D 64
#define LN_EPS 1e-5f
#define SCAN_CH 1024
#define WFIX 262144.0f    // 2^18 fixed-point scale for wsum
#define CNT_SH 25         // count in bits 25..31, wsum in bits 0..24
#define WSUM_MASK ((1u << CNT_SH) - 1)
#define WQ_BITS 15        // csr weight quantization (w in [0,1))
#define WQ_SCALE 32768.0f
#define NB 1024           // coarse buckets (bucket = dst >> BSH)
#define BSH 7             // 128 nodes per bucket
#define GP 256            // partition grid blocks
#define GB2 2048          // gather grid blocks (8192 waves = max occupancy)

// ---------------------------------------------------------------------------
// 7-launch pipeline (NO cooperative launch — it fails in this harness):
//  k_hist1: per-block LDS hist over 1024 buckets
//  k_scanb: per-bucket exclusive scan over 256 block counts (1 wave/bucket)
//  k_part2: redundant LDS scan of bucket totals (+total2 out, block 0) ->
//           partition edges into contiguous per-(bucket,block) ranges
//  k_emit:  per-bucket: LDS cnt|wsum -> packed, nstart, compact csr
//  k_gemm:  y = dis * xW (fp16)
//  k_gather2: grid-strided, scalar-uniform csr loads, block partials
//  k_ln2:   redundant reduce of 2048 partials -> LN + ReLU
// rec u64: hi = dst_local(7) | wfix(19)<<7 ; lo = src(17)<<15 | wq(15)
// ---------------------------------------------------------------------------

__global__ __launch_bounds__(256) void k_hist1(const int* __restrict__ ei, int E,
                                               int* __restrict__ hist) {
    __shared__ int h[NB];
    for (int i = threadIdx.x; i < NB; i += 256) h[i] = 0;
    __syncthreads();
    int chunk = (E + GP - 1) / GP;
    int s0 = blockIdx.x * chunk;
    int s1 = min(E, s0 + chunk);
    for (int e = s0 + threadIdx.x; e < s1; e += 256)
        atomicAdd(&h[((unsigned int)ei[E + e]) >> BSH], 1);
    __syncthreads();
    for (int i = threadIdx.x; i < NB; i += 256)
        hist[i * GP + blockIdx.x] = h[i];          // bucket-major
}

__global__ __launch_bounds__(256) void k_scanb(int* __restrict__ hist,
                                               int* __restrict__ total) {
    int lane = threadIdx.x & 63, wv = threadIdx.x >> 6;
    int bucket = blockIdx.x * 4 + wv;
    int4 c = *(int4*)&hist[bucket * GP + lane * 4];
    int lsum = c.x + c.y + c.z + c.w;
    int sum = lsum;
#pragma unroll
    for (int off2 = 1; off2 < 64; off2 <<= 1) {
        int t = __shfl_up(sum, off2);
        if (lane >= off2) sum += t;
    }
    int base = sum - lsum;
    int4 o;
    o.x = base; o.y = base + c.x; o.z = o.y + c.y; o.w = o.z + c.z;
    *(int4*)&hist[bucket * GP + lane * 4] = o;     // exclusive offsets in place
    if (lane == 63) total[bucket] = sum;           // raw bucket totals
}

// partition edges; computes its own exclusive scan of total[] in LDS
__global__ __launch_bounds__(256) void k_part2(const int* __restrict__ ei,
                                               const float* __restrict__ w,
                                               const int* __restrict__ hist,
                                               const int* __restrict__ total,
                                               int* __restrict__ total2,
                                               unsigned long long* __restrict__ part,
                                               int E) {
    __shared__ int shB[NB];
    __shared__ int shA[NB];
    __shared__ int wt4[4];
    int tid = threadIdx.x;
    int lane = tid & 63, wv = tid >> 6;
    // exclusive scan of total[NB] -> shB (identical in every block)
    {
        int4 c4v = *(const int4*)&total[tid * 4];
        int lsum = c4v.x + c4v.y + c4v.z + c4v.w;
        int sum = lsum;
#pragma unroll
        for (int o2 = 1; o2 < 64; o2 <<= 1) {
            int t = __shfl_up(sum, o2);
            if (lane >= o2) sum += t;
        }
        if (lane == 63) wt4[wv] = sum;
        __syncthreads();
        int woff = 0;
#pragma unroll
        for (int k = 0; k < 4; ++k) if (k < wv) woff += wt4[k];
        int base = woff + sum - lsum;
        shB[tid * 4 + 0] = base;
        shB[tid * 4 + 1] = base + c4v.x;
        shB[tid * 4 + 2] = base + c4v.x + c4v.y;
        shB[tid * 4 + 3] = base + c4v.x + c4v.y + c4v.z;
    }
    __syncthreads();
    if (blockIdx.x == 0)
        *(int4*)&total2[tid * 4] = *(const int4*)&shB[tid * 4];
    for (int i = tid; i < NB; i += 256)
        shA[i] = shB[i] + hist[i * GP + blockIdx.x];
    __syncthreads();
    int chunk = (E + GP - 1) / GP;
    int s0 = blockIdx.x * chunk;
    int s1 = min(E, s0 + chunk);
    for (int e = s0 + tid; e < s1; e += 256) {
        unsigned int dst = (unsigned int)ei[E + e];
        unsigned int src = (unsigned int)ei[e];
        float wf = w[e];
        int pos = atomicAdd(&shA[dst >> BSH], 1);
        unsigned int wq = __float2uint_rn(wf * WQ_SCALE);
        if (wq > 32767u) wq = 32767u;
        unsigned int wfix = __float2uint_rn(wf * WFIX);
        unsigned int lo = (src << WQ_BITS) | wq;
        unsigned int hi = (dst & ((1u << BSH) - 1)) | (wfix << BSH);
        part[pos] = ((unsigned long long)hi << 32) | lo;
    }
}

// per-bucket: counts/wsum in LDS -> packed + nstart + compact csr
__global__ __launch_bounds__(256) void k_emit(const unsigned long long* __restrict__ part,
                                              const int* __restrict__ total2,
                                              unsigned int* __restrict__ packed,
                                              int* __restrict__ nstart,
                                              unsigned int* __restrict__ csr,
                                              int N, int E) {
    __shared__ unsigned int cw[1 << BSH];
    __shared__ int cursor[1 << BSH];
    __shared__ int wtot[2];
    int b = blockIdx.x;
    int beg = total2[b];
    int end = (b == NB - 1) ? E : total2[b + 1];
    int tid = threadIdx.x;
    if (tid < (1 << BSH)) cw[tid] = 0;
    __syncthreads();
    for (int i = beg + tid; i < end; i += 256) {
        unsigned int hi = (unsigned int)(part[i] >> 32);
        atomicAdd(&cw[hi & 127u], (1u << CNT_SH) | (hi >> BSH));
    }
    __syncthreads();
    int lane = tid & 63, wv = tid >> 6;
    if (tid < 128) {
        unsigned int p = cw[tid];
        int cnt = (int)(p >> CNT_SH);
        int sum = cnt;
#pragma unroll
        for (int o2 = 1; o2 < 64; o2 <<= 1) {
            int t = __shfl_up(sum, o2);
            if (lane >= o2) sum += t;
        }
        if (lane == 63) wtot[wv] = sum;
        cursor[tid] = sum - cnt;
        int node = (b << BSH) + tid;
        if (node < N) packed[node] = p;
    }
    __syncthreads();
    if (tid < 128) {
        int st = cursor[tid] + beg + ((wv == 1) ? wtot[0] : 0);
        cursor[tid] = st;
        int node = (b << BSH) + tid;
        if (node < N) nstart[node] = st;
    }
    __syncthreads();
    for (int i = beg + tid; i < end; i += 256) {
        unsigned long long r = part[i];
        unsigned int hi = (unsigned int)(r >> 32);
        int pos = atomicAdd(&cursor[hi & 127u], 1);
        csr[pos] = (unsigned int)r;
    }
}

// ---- y[n,c] = dis[n] * sum_k x[n,k]*W[c,k], output fp16 -------------------
__global__ __launch_bounds__(256, 4) void k_gemm(const float* __restrict__ x,
                                                 const float* __restrict__ W,
                                                 const unsigned int* __restrict__ packed,
                                                 __half* __restrict__ y, int N) {
    __shared__ float Ws[D * 68];
    __shared__ float xs[64 * 68];
    int tid = threadIdx.x;
    int rowBase = blockIdx.x * 64;
#pragma unroll
    for (int i = 0; i < 16; ++i) {
        int idx = i * 256 + tid;
        int a = idx >> 6, kk = idx & 63;
        Ws[a * 68 + kk] = W[idx];
        int row = rowBase + a;
        xs[a * 68 + kk] = (row < N) ? x[idx + rowBase * D] : 0.0f;
    }
    __syncthreads();
    int l = tid & 63, wv = tid >> 6;
    int g = l >> 4;
    int c1 = l & 15;
    int r0 = wv * 16 + g * 4;
    float acc[4][4];
#pragma unroll
    for (int a = 0; a < 4; ++a)
#pragma unroll
        for (int bj = 0; bj < 4; ++bj) acc[a][bj] = 0.0f;
#pragma unroll 2
    for (int kc = 0; kc < 16; ++kc) {
        int k0 = kc * 4;
        float4 xr[4], wr[4];
#pragma unroll
        for (int jr = 0; jr < 4; ++jr)
            xr[jr] = *(const float4*)&xs[(r0 + jr) * 68 + k0];
#pragma unroll
        for (int jc = 0; jc < 4; ++jc)
            wr[jc] = *(const float4*)&Ws[(c1 + 16 * jc) * 68 + k0];
#pragma unroll
        for (int jr = 0; jr < 4; ++jr)
#pragma unroll
            for (int jc = 0; jc < 4; ++jc)
                acc[jr][jc] += xr[jr].x * wr[jc].x + xr[jr].y * wr[jc].y +
                               xr[jr].z * wr[jc].z + xr[jr].w * wr[jc].w;
    }
#pragma unroll
    for (int jr = 0; jr < 4; ++jr) {
        int row = rowBase + r0 + jr;
        if (row < N) {
            float dr = rsqrtf(1.0f +
                (float)(packed[row] & WSUM_MASK) * (1.0f / WFIX));
#pragma unroll
            for (int jc = 0; jc < 4; ++jc)
                y[row * D + c1 + 16 * jc] = __float2half_rn(acc[jr][jc] * dr);
        }
    }
}

// ---- gather: grid-strided waves; wave-uniform scalar csr loads ------------
__global__ __launch_bounds__(256) void k_gather2(const unsigned int* __restrict__ packed,
                                                 const int* __restrict__ nstart,
                                                 const unsigned int* __restrict__ csr,
                                                 const __half* __restrict__ y,
                                                 const float* __restrict__ bias,
                                                 float* __restrict__ out,
                                                 float* __restrict__ partial, int N) {
    int tid = threadIdx.x;
    int lane = tid & 63, wv = tid >> 6;
    int gwave = blockIdx.x * 4 + wv;
    int nwaves = gridDim.x * 4;
    float s = 0.0f, ss = 0.0f;
    const float wsc = 1.0f / WQ_SCALE;
    float bl = bias[lane];
    for (int n = gwave; n < N; n += nwaves) {
        unsigned int p = packed[n];
        int m = __builtin_amdgcn_readfirstlane((int)(p >> CNT_SH));
        int su = __builtin_amdgcn_readfirstlane(nstart[n]);
        float dis_n = rsqrtf(1.0f + (float)(p & WSUM_MASK) * (1.0f / WFIX));
        float acc = __half2float(y[(size_t)n * D + lane]);   // self-loop term
        int j = 0;
        for (; j + 3 < m; j += 4) {
            unsigned int p0 = csr[su + j];
            unsigned int p1 = csr[su + j + 1];
            unsigned int p2 = csr[su + j + 2];
            unsigned int p3 = csr[su + j + 3];
            float a0 = __half2float(y[(size_t)(p0 >> WQ_BITS) * D + lane]);
            float a1 = __half2float(y[(size_t)(p1 >> WQ_BITS) * D + lane]);
            float a2 = __half2float(y[(size_t)(p2 >> WQ_BITS) * D + lane]);
            float a3 = __half2float(y[(size_t)(p3 >> WQ_BITS) * D + lane]);
            acc += (float)(p0 & 32767u) * wsc * a0;
            acc += (float)(p1 & 32767u) * wsc * a1;
            acc += (float)(p2 & 32767u) * wsc * a2;
            acc += (float)(p3 & 32767u) * wsc * a3;
        }
        for (; j < m; ++j) {
            unsigned int p0 = csr[su + j];
            acc += (float)(p0 & 32767u) * wsc *
                   __half2float(y[(size_t)(p0 >> WQ_BITS) * D + lane]);
        }
        float o = dis_n * acc + bl;
        out[(size_t)n * D + lane] = o;
        s += o;
        ss += o * o;
    }
#pragma unroll
    for (int off = 32; off; off >>= 1) {
        s += __shfl_down(s, off);
        ss += __shfl_down(ss, off);
    }
    __shared__ float ls[4], lss[4];
    if (lane == 0) { ls[wv] = s; lss[wv] = ss; }
    __syncthreads();
    if (tid == 0) {
        partial[2 * blockIdx.x]     = ls[0] + ls[1] + ls[2] + ls[3];
        partial[2 * blockIdx.x + 1] = lss[0] + lss[1] + lss[2] + lss[3];
    }
}

// ---- LN + ReLU with redundant per-block reduction of 2048 partials --------
__global__ __launch_bounds__(256) void k_ln2(float* __restrict__ out,
                                             const float* __restrict__ gamma,
                                             const float* __restrict__ beta,
                                             const float* __restrict__ partial,
                                             int N) {
    __shared__ double dls[4], dlss[4];
    __shared__ float mu_s, isd_s;
    int tid = threadIdx.x;
    int lane = tid & 63, wv = tid >> 6;
    double ds = 0.0, dss = 0.0;
    for (int i = tid; i < GB2; i += 256) {
        ds += (double)partial[2 * i];
        dss += (double)partial[2 * i + 1];
    }
#pragma unroll
    for (int off = 32; off; off >>= 1) {
        ds += __shfl_down(ds, off);
        dss += __shfl_down(dss, off);
    }
    if (lane == 0) { dls[wv] = ds; dlss[wv] = dss; }
    __syncthreads();
    if (tid == 0) {
        double S = dls[0] + dls[1] + dls[2] + dls[3];
        double SS = dlss[0] + dlss[1] + dlss[2] + dlss[3];
        double M = (double)N * (double)D;
        double mu = S / M;
        double var = SS / M - mu * mu;
        mu_s = (float)mu;
        isd_s = (float)(1.0 / sqrt(var + (double)LN_EPS));
    }
    __syncthreads();
    float muf = mu_s, isd = isd_s;
    int nchunks = N * (D / 4);
    int i = blockIdx.x * 256 + tid;
    if (i >= nchunks) return;
    int c4 = (i & 15) * 4;
    float4 v = ((float4*)out)[i];
    v.x = fmaxf((v.x - muf) * isd * gamma[c4 + 0] + beta[c4 + 0], 0.0f);
    v.y = fmaxf((v.y - muf) * isd * gamma[c4 + 1] + beta[c4 + 1], 0.0f);
    v.z = fmaxf((v.z - muf) * isd * gamma[c4 + 2] + beta[c4 + 2], 0.0f);
    v.w = fmaxf((v.w - muf) * isd * gamma[c4 + 3] + beta[c4 + 3], 0.0f);
    ((float4*)out)[i] = v;
}

// ---- fallback kernels (atomic scatter path) -------------------------------
__global__ __launch_bounds__(256) void k_build(const int* __restrict__ ei,
                                               const float* __restrict__ w,
                                               unsigned int* __restrict__ packed,
                                               int E) {
    int e = blockIdx.x * blockDim.x + threadIdx.x;
    if (e < E) {
        unsigned int v = (1u << CNT_SH) | __float2uint_rn(w[e] * WFIX);
        atomicAdd(&packed[ei[E + e]], v);
    }
}

__global__ __launch_bounds__(256) void k_scatter(const int* __restrict__ ei,
                                                 const float* __restrict__ w,
                                                 const __half* __restrict__ y,
                                                 float* __restrict__ out, int E) {
    int t = blockIdx.x * blockDim.x + threadIdx.x;
    int e = t >> 6;
    int lane = t & 63;
    if (e >= E) return;
    float v = w[e] * __half2float(y[(size_t)ei[e] * D + lane]);
    unsafeAtomicAdd(&out[(size_t)ei[E + e] * D + lane], v);
}

__global__ __launch_bounds__(256) void k_seed(const __half* __restrict__ y,
                                              float* __restrict__ out, int total) {
    int i = blockIdx.x * blockDim.x + threadIdx.x;
    if (i < total) out[i] = __half2float(y[i]);
}

__global__ __launch_bounds__(256) void k_finalize(float* __restrict__ out,
                                                  const unsigned int* __restrict__ packed,
                                                  const float* __restrict__ b,
                                                  double* __restrict__ scal, int N) {
    int nchunks = N * (D / 4);
    float s = 0.0f, ss = 0.0f;
    float4* o4 = (float4*)out;
    for (int i = blockIdx.x * blockDim.x + threadIdx.x; i < nchunks;
         i += gridDim.x * blockDim.x) {
        int row = i >> 4;
        int c4 = (i & 15) * 4;
        float4 v = o4[i];
        float dr = rsqrtf(1.0f + (float)(packed[row] & WSUM_MASK) * (1.0f / WFIX));
        v.x = dr * v.x + b[c4 + 0];
        v.y = dr * v.y + b[c4 + 1];
        v.z = dr * v.z + b[c4 + 2];
        v.w = dr * v.w + b[c4 + 3];
        o4[i] = v;
        s += v.x + v.y + v.z + v.w;
        ss += v.x * v.x + v.y * v.y + v.z * v.z + v.w * v.w;
    }
#pragma unroll
    for (int off = 32; off; off >>= 1) {
        s += __shfl_down(s, off);
        ss += __shfl_down(ss, off);
    }
    __shared__ float ls[4], lss[4];
    int lane = threadIdx.x & 63, wv = threadIdx.x >> 6;
    if (lane == 0) { ls[wv] = s; lss[wv] = ss; }
    __syncthreads();
    if (threadIdx.x == 0) {
        atomicAdd(&scal[0], (double)(ls[0] + ls[1] + ls[2] + ls[3]));
        atomicAdd(&scal[1], (double)(lss[0] + lss[1] + lss[2] + lss[3]));
    }
}

__global__ __launch_bounds__(256) void k_ln(float* __restrict__ out,
                                            const float* __restrict__ gamma,
                                            const float* __restrict__ beta,
                                            const double* __restrict__ scal, int N) {
    int nchunks = N * (D / 4);
    int i = blockIdx.x * blockDim.x + threadIdx.x;
    if (i >= nchunks) return;
    double M = (double)N * (double)D;
    double mu = scal[0] / M;
    double var = scal[1] / M - mu * mu;
    float muf = (float)mu;
    float isd = (float)(1.0 / sqrt(var + (double)LN_EPS));
    int c4 = (i & 15) * 4;
    float4 v = ((float4*)out)[i];
    v.x = fmaxf((v.x - muf) * isd * gamma[c4 + 0] + beta[c4 + 0], 0.0f);
    v.y = fmaxf((v.y - muf) * isd * gamma[c4 + 1] + beta[c4 + 1], 0.0f);
    v.z = fmaxf((v.z - muf) * isd * gamma[c4 + 2] + beta[c4 + 2], 0.0f);
    v.w = fmaxf((v.w - muf) * isd * gamma[c4 + 3] + beta[c4 + 3], 0.0f);
    ((float4*)out)[i] = v;
}

extern "C" void kernel_launch(void* const* d_in, const int* in_sizes, int n_in,
                              void* d_out, int out_size, void* d_ws, size_t ws_size,
                              hipStream_t stream) {
    const float* x     = (const float*)d_in[0];
    const int*   ei    = (const int*)d_in[1];
    const float* ew    = (const float*)d_in[2];
    const float* W     = (const float*)d_in[3];
    const float* b     = (const float*)d_in[4];
    const float* gamma = (const float*)d_in[5];
    const float* beta  = (const float*)d_in[6];
    float* out = (float*)d_out;

    int N = in_sizes[0] / D;
    int E = in_sizes[2];

    char* ws = (char*)d_ws;
    size_t off = 0;
    unsigned int* packed = (unsigned int*)(ws + off); off += (size_t)N * 4;
    int* nstart  = (int*)(ws + off);    off += (size_t)N * 4;
    off = (off + 255) & ~(size_t)255;
    int* hist    = (int*)(ws + off);    off += (size_t)NB * GP * 4;
    int* total   = (int*)(ws + off);    off += (size_t)NB * 4;
    int* total2  = (int*)(ws + off);    off += (size_t)NB * 4;
    double* scal = (double*)(ws + off); off += 16;
    float* partial = (float*)(ws + off); off += (size_t)GB2 * 8;
    off = (off + 255) & ~(size_t)255;
    size_t partBytes = (size_t)E * 8;
    size_t yBytes = (size_t)N * D * 2;
    unsigned long long* part = (unsigned long long*)(ws + off);
    __half* y = (__half*)(ws + off);
    off += (partBytes > yBytes) ? partBytes : yBytes;   // part dead before gemm
    off = (off + 255) & ~(size_t)255;
    unsigned int* csr = (unsigned int*)(ws + off); off += (size_t)E * 4;

    int nbu = (N + (1 << BSH) - 1) >> BSH;
    bool csr_path = (ws_size >= off) && (nbu <= NB) &&
                    (N < (1 << (32 - WQ_BITS))) &&
                    ((size_t)E <= (size_t)N * 24);

    if (csr_path) {
        k_hist1<<<GP, 256, 0, stream>>>(ei, E, hist);
        k_scanb<<<NB / 4, 256, 0, stream>>>(hist, total);
        k_part2<<<GP, 256, 0, stream>>>(ei, ew, hist, total, total2, part, E);
        k_emit<<<nbu, 256, 0, stream>>>(part, total2, packed, nstart, csr, N, E);
        k_gemm<<<(N + 63) / 64, 256, 0, stream>>>(x, W, packed, y, N);
        k_gather2<<<GB2, 256, 0, stream>>>(packed, nstart, csr, y, b, out,
                                           partial, N);
        k_ln2<<<(N * (D / 4) + 255) / 256, 256, 0, stream>>>(out, gamma, beta,
                                                             partial, N);
    } else {
        hipMemsetAsync(packed, 0, (size_t)N * 4, stream);
        hipMemsetAsync(scal, 0, 16, stream);
        k_build<<<(E + 255) / 256, 256, 0, stream>>>(ei, ew, packed, E);
        k_gemm<<<(N + 63) / 64, 256, 0, stream>>>(x, W, packed, y, N);
        k_seed<<<(N * D + 255) / 256, 256, 0, stream>>>(y, out, N * D);
        k_scatter<<<(E + 3) / 4, 256, 0, stream>>>(ei, ew, y, out, E);
        k_finalize<<<2048, 256, 0, stream>>>(out, packed, b, scal, N);
        k_ln<<<(N * (D / 4) + 255) / 256, 256, 0, stream>>>(out, gamma, beta, scal, N);
    }
}